// Round 9
// baseline (272.940 us; speedup 1.0000x reference)
//
#include <hip/hip_runtime.h>
#include <hip/hip_bf16.h>
#include <cstdint>

#define DEVINL static __device__ __forceinline__

typedef __attribute__((ext_vector_type(4))) float floatx4;
typedef __attribute__((ext_vector_type(8))) short bf16x8;

DEVINL unsigned short f2bf(float f) {
    union { float f; uint32_t u; } v; v.f = f;
    return (unsigned short)((v.u + 0x7FFFu + ((v.u >> 16) & 1u)) >> 16);
}

DEVINL uint32_t pk2bf(float x, float y) {
    __hip_bfloat162 h = __float22bfloat162_rn(float2{x, y});
    union { __hip_bfloat162 h; uint32_t u; } v; v.h = h;
    return v.u;
}

DEVINL floatx4 mfma16(bf16x8 a, bf16x8 b, floatx4 c) {
    return __builtin_amdgcn_mfma_f32_16x16x32_bf16(a, b, c, 0, 0, 0);
}

// async global->LDS DMA, 16B per lane. LDS dest must be base + lane*16 contiguous.
#define GLDS16(g, l)                                                            \
    __builtin_amdgcn_global_load_lds(                                           \
        (const __attribute__((address_space(1))) void*)(g),                     \
        (__attribute__((address_space(3))) void*)(l), 16, 0, 0)

// ---- problem constants ----
constexpr int B_ = 2, S_ = 2048, D_ = 1024, H_ = 16, DK_ = 64;
constexpr int BSROWS = B_ * S_;  // 4096
constexpr int NQB = S_ / 128;    // 16 q-blocks
constexpr int NKT = S_ / 64;     // 32 k-tiles

// Q pre-scale: 1/sqrt(d_k) * log2(e), so softmax uses raw v_exp_f32 (exp2).
constexpr float QSCALE = 0.18033688011112042f;

// per-tile mask flags (1 = all-nonzero tile -> fast path). Rewritten every call.
__device__ int g_flags[B_ * NQB * NKT];

// ================= fused QKV projection GEMM + mask flags ====================
// Round 13 (T14 ordering fix): rounds 7/8 were invariant at ~71 us across
// BK/occupancy because loadStage(it+2)'s global loads CROSSED a __syncthreads
// -> compiler's pre-barrier s_waitcnt vmcnt(0) drained them every iteration
// (m97 semantics), serializing full L2 latency per iter. Fix: issue
// loadStage(it+1) at the TOP of the interval, consume it in writeStage at the
// BOTTOM of the SAME interval (32 MFMA + 16 ds_read of compute cover the
// latency). No load lives across a barrier. BK=64 (longer cover window),
// 2 blocks/CU. Mask-flag blocks moved to ids 0..1023 (front) so their 33 MB
// streams under the GEMM prologue instead of tailing the dispatch.
// Epilogues unchanged: z0 -> Qp *QSCALE, z1 -> KpF frag-tiled, z2 -> VpF.
__global__ __launch_bounds__(256, 2)
void gemm_qkv(const float* __restrict__ q, const float* __restrict__ k,
              const float* __restrict__ v,
              const float* __restrict__ Wq, const float* __restrict__ Wk,
              const float* __restrict__ Wv,
              const float* __restrict__ bq, const float* __restrict__ bk,
              const float* __restrict__ bv,
              const int* __restrict__ mask,
              unsigned short* __restrict__ Qp, unsigned short* __restrict__ KpF,
              unsigned short* __restrict__ VpF)
{
    constexpr int K = D_, N = D_;
    __shared__ unsigned short As[2][128 * 64];
    __shared__ unsigned short Bs[2][128 * 64];
    __shared__ int fflag;

    const int bid = blockIdx.x;

    // ---------------- mask-flag blocks (bid < 1024, front of dispatch) ------
    if (bid < 1024) {
        int mb = bid;                         // (b*16 + qb)*32 + kt
        int kt = mb & 31, qq = (mb >> 5) & 15, b = mb >> 9;
        const int* base = mask + (size_t)(b * S_ + qq * 128) * S_ + kt * 64;
        int ok = 1;
        #pragma unroll
        for (int i = 0; i < 8; ++i) {
            int u = threadIdx.x + 256 * i;
            int row = u >> 4, c = u & 15;
            int4 m = *(const int4*)(base + (size_t)row * S_ + c * 4);
            if ((m.x == 0) | (m.y == 0) | (m.z == 0) | (m.w == 0)) ok = 0;
        }
        if (threadIdx.x == 0) fflag = 1;
        __syncthreads();
        if (!ok) fflag = 0;
        __syncthreads();
        if (threadIdx.x == 0) g_flags[mb] = fflag;
        return;
    }

    // ---------------- GEMM blocks (bid >= 1024) ----------------
    const int gb = bid - 1024;                  // 0..767
    const int xcd = gb & 7, sl = gb >> 3;       // sl 0..95
    const int z = sl >> 5, rr = sl & 31;
    const int nb = rr >> 2, mloc = rr & 3;
    const int m0 = (mloc * 8 + xcd) * 128, n0 = nb * 128;

    const float* A    = z == 0 ? q  : z == 1 ? k  : v;
    const float* W    = z == 0 ? Wq : z == 1 ? Wk : Wv;
    const float* bias = z == 0 ? bq : z == 1 ? bk : bv;

    const int tid  = threadIdx.x;
    const int lane = tid & 63, wave = tid >> 6;
    const int lr = lane & 15, lg = lane >> 4;
    const int wm = (wave >> 1) * 64, wn = (wave & 1) * 64;

    // lane-constant stage descriptors (XOR-8 chunk swizzle, GLDS16-compatible)
    int rowA[4], kcA[4];
    #pragma unroll
    for (int j = 0; j < 4; ++j) {
        int L = (wave * 4 + j) * 64 + lane;
        rowA[j] = L >> 3; kcA[j] = (L & 7) ^ (rowA[j] & 7);
    }

    float4 ra[4][2], rw[4][2];
    auto loadStage = [&](int k0) {
        #pragma unroll
        for (int j = 0; j < 4; ++j) {
            const float* pa = A + (size_t)(m0 + rowA[j]) * K + k0 + kcA[j] * 8;
            ra[j][0] = *(const float4*)pa;
            ra[j][1] = *(const float4*)(pa + 4);
            const float* pw = W + (size_t)(n0 + rowA[j]) * K + k0 + kcA[j] * 8;
            rw[j][0] = *(const float4*)pw;
            rw[j][1] = *(const float4*)(pw + 4);
        }
    };
    auto writeStage = [&](int buf) {
        #pragma unroll
        for (int j = 0; j < 4; ++j) {
            uint4 o;
            o.x = pk2bf(ra[j][0].x, ra[j][0].y); o.y = pk2bf(ra[j][0].z, ra[j][0].w);
            o.z = pk2bf(ra[j][1].x, ra[j][1].y); o.w = pk2bf(ra[j][1].z, ra[j][1].w);
            *(uint4*)&As[buf][(wave * 4 + j) * 512 + lane * 8] = o;
            uint4 p;
            p.x = pk2bf(rw[j][0].x, rw[j][0].y); p.y = pk2bf(rw[j][0].z, rw[j][0].w);
            p.z = pk2bf(rw[j][1].x, rw[j][1].y); p.w = pk2bf(rw[j][1].z, rw[j][1].w);
            *(uint4*)&Bs[buf][(wave * 4 + j) * 512 + lane * 8] = p;
        }
    };

    floatx4 acc[4][4];
    #pragma unroll
    for (int mt = 0; mt < 4; ++mt)
        #pragma unroll
        for (int nt = 0; nt < 4; ++nt)
            acc[mt][nt] = floatx4{0.f, 0.f, 0.f, 0.f};

    // prologue: tile 0 staged; no load crosses the barrier
    loadStage(0);
    writeStage(0);
    __syncthreads();
    for (int it = 0; it < K / 64; ++it) {
        const int buf = it & 1;
        if (it + 1 < K / 64) loadStage((it + 1) * 64);   // issue at interval TOP

        #pragma unroll
        for (int kf = 0; kf < 2; ++kf) {
            bf16x8 af[4], bfr[4];
            #pragma unroll
            for (int mt = 0; mt < 4; ++mt) {
                int row = wm + mt * 16 + lr;
                af[mt] = *(const bf16x8*)&As[buf][row * 64 + (((kf * 4 + lg) ^ (lr & 7)) * 8)];
            }
            #pragma unroll
            for (int nt = 0; nt < 4; ++nt) {
                int row = wn + nt * 16 + lr;
                bfr[nt] = *(const bf16x8*)&Bs[buf][row * 64 + (((kf * 4 + lg) ^ (lr & 7)) * 8)];
            }
            #pragma unroll
            for (int mt = 0; mt < 4; ++mt)
                #pragma unroll
                for (int nt = 0; nt < 4; ++nt)
                    acc[mt][nt] = mfma16(af[mt], bfr[nt], acc[mt][nt]);
        }

        if (it + 1 < K / 64) writeStage(buf ^ 1);        // consume SAME interval
        __syncthreads();
    }

    // ---- epilogues (C/D layout: col=lane&15, row=quad*4+reg) ----
    if (z == 0) {
        #pragma unroll
        for (int nt = 0; nt < 4; ++nt) {
            int col = n0 + wn + nt * 16 + lr;
            float bv2 = bias[col];
            #pragma unroll
            for (int mt = 0; mt < 4; ++mt)
                #pragma unroll
                for (int reg = 0; reg < 4; ++reg) {
                    int row = m0 + wm + mt * 16 + lg * 4 + reg;
                    Qp[(size_t)row * N + col] = f2bf((acc[mt][nt][reg] + bv2) * QSCALE);
                }
        }
    } else if (z == 1) {
        #pragma unroll
        for (int nt = 0; nt < 4; ++nt) {
            int c = n0 + wn + nt * 16 + lr;
            int h = c >> 6, d = c & 63;
            int kfA = d >> 5, lgA = (d >> 3) & 3, j = d & 7;
            float bv2 = bias[c];
            #pragma unroll
            for (int mt = 0; mt < 4; ++mt)
                #pragma unroll
                for (int reg = 0; reg < 4; ++reg) {
                    int t = m0 + wm + mt * 16 + lg * 4 + reg;
                    int bb = t >> 11, sx = t & (S_ - 1);
                    int kt = sx >> 6, key = sx & 63;
                    int mtA = key >> 4, lrA = key & 15;
                    size_t off = (((size_t)(bb * 16 + h) * 32 + kt) * 8 + (kfA * 4 + mtA)) * 512
                               + (lrA + 16 * lgA) * 8 + j;
                    KpF[off] = f2bf(acc[mt][nt][reg] + bv2);
                }
        }
    } else {
        #pragma unroll
        for (int nt = 0; nt < 4; ++nt) {
            int c = n0 + wn + nt * 16 + lr;
            int h = c >> 6, dtA = (c >> 4) & 3;   // lrA == lr
            float bv2 = bias[c];
            #pragma unroll
            for (int mt = 0; mt < 4; ++mt) {
                int t0 = m0 + wm + mt * 16 + lg * 4;
                int bb = t0 >> 11, s0 = t0 & (S_ - 1);
                int kt = s0 >> 6, key = s0 & 63;
                int kfA = key >> 5, lgA = (key >> 3) & 3, j0 = key & 7;
                size_t off = (((size_t)(bb * 16 + h) * 32 + kt) * 8 + (dtA * 2 + kfA)) * 512
                           + (lr + 16 * lgA) * 8 + j0;
                uint2 p;
                p.x = pk2bf(acc[mt][nt][0] + bv2, acc[mt][nt][1] + bv2);
                p.y = pk2bf(acc[mt][nt][2] + bv2, acc[mt][nt][3] + bv2);
                *(uint2*)&VpF[off] = p;
            }
        }
    }
}

// ================= Flash attention: zero-barrier, pipelined fragment loads ===
// (verified config: 4 waves x 32 q-rows, 2 blocks/CU; 1-D grid so the
// co-resident pair (id, id+256) shares (h,b) for L1/L2-hot K/V streams;
// id%8 == h%8 keeps XCD clustering. Reg double-buffered K/V prefetch,
// fixed-max exp2 softmax, wave-private P in LDS, no barriers in loop.)
__global__ __launch_bounds__(256, 2)
void attn_flash(const unsigned short* __restrict__ Qp,
                const unsigned short* __restrict__ KpF,
                const unsigned short* __restrict__ VpF,
                const int* __restrict__ mask,
                unsigned short* __restrict__ Out)
{
    constexpr int LD = 72;
    __shared__ unsigned short Ps[128 * LD];

    const int tid = threadIdx.x;
    const int lane = tid & 63, wave = tid >> 6;
    const int lr = lane & 15, lg = lane >> 4;
    const int id = blockIdx.x;                 // 0..511
    const int hb = id & 31;                    // h + 16*b
    const int h = hb & 15, b = hb >> 4;
    const int qb = ((id >> 8) << 3) | ((id >> 5) & 7);
    const int q0 = qb * 128, qw = q0 + wave * 32;

    bf16x8 qf[2][2];
    #pragma unroll
    for (int qt = 0; qt < 2; ++qt)
        #pragma unroll
        for (int kf = 0; kf < 2; ++kf)
            qf[qt][kf] = *(const bf16x8*)(Qp + (size_t)(b * S_ + qw + qt * 16 + lr) * D_ +
                                          h * DK_ + kf * 32 + lg * 8);

    float l_[2] = {0.f, 0.f};
    floatx4 o_acc[2][4];
    #pragma unroll
    for (int qt = 0; qt < 2; ++qt)
        #pragma unroll
        for (int dt = 0; dt < 4; ++dt) o_acc[qt][dt] = floatx4{0.f, 0.f, 0.f, 0.f};

    const unsigned short* kbase = KpF + (size_t)(b * 16 + h) * 32 * 4096 + lane * 8;
    const unsigned short* vbase = VpF + (size_t)(b * 16 + h) * 32 * 4096 + lane * 8;
    const int fbase = (b * NQB + qb) * NKT;
    unsigned short* PsW = &Ps[(wave * 32 + lr) * LD];

    auto loadKV = [&](int kt, bf16x8 (&kfr)[8], bf16x8 (&vfr)[8]) {
        const unsigned short* kb = kbase + kt * 4096;
        const unsigned short* vb = vbase + kt * 4096;
        #pragma unroll
        for (int c = 0; c < 8; ++c) kfr[c] = *(const bf16x8*)(kb + c * 512);
        #pragma unroll
        for (int c = 0; c < 8; ++c) vfr[c] = *(const bf16x8*)(vb + c * 512);
    };

    auto process = [&](int kt, bf16x8 (&kfr)[8], bf16x8 (&vfr)[8]) {
        floatx4 sc[2][4];
        #pragma unroll
        for (int qt = 0; qt < 2; ++qt)
            #pragma unroll
            for (int mt = 0; mt < 4; ++mt) sc[qt][mt] = floatx4{0.f, 0.f, 0.f, 0.f};
        #pragma unroll
        for (int mt = 0; mt < 4; ++mt)
            #pragma unroll
            for (int kf = 0; kf < 2; ++kf)
                #pragma unroll
                for (int qt = 0; qt < 2; ++qt)
                    sc[qt][mt] = mfma16(kfr[kf * 4 + mt], qf[qt][kf], sc[qt][mt]);

        if (g_flags[fbase + kt] == 0) {
            #pragma unroll
            for (int qt = 0; qt < 2; ++qt) {
                int qq = qw + qt * 16 + lr;
                const int* mrow = mask + (size_t)(b * S_ + qq) * S_ + kt * 64;
                #pragma unroll
                for (int mt = 0; mt < 4; ++mt)
                    #pragma unroll
                    for (int reg = 0; reg < 4; ++reg)
                        if (mrow[mt * 16 + lg * 4 + reg] == 0)
                            sc[qt][mt][reg] = -1e9f;
            }
        }

        #pragma unroll
        for (int qt = 0; qt < 2; ++qt) {
            #pragma unroll
            for (int mt = 0; mt < 4; ++mt) {
                float p0 = __builtin_amdgcn_exp2f(sc[qt][mt][0]);
                float p1 = __builtin_amdgcn_exp2f(sc[qt][mt][1]);
                float p2 = __builtin_amdgcn_exp2f(sc[qt][mt][2]);
                float p3 = __builtin_amdgcn_exp2f(sc[qt][mt][3]);
                l_[qt] += (p0 + p1) + (p2 + p3);
                uint2 pk; pk.x = pk2bf(p0, p1); pk.y = pk2bf(p2, p3);
                *(uint2*)&PsW[qt * 16 * LD + mt * 16 + lg * 4] = pk;
            }
        }

        bf16x8 pb[2][2];
        #pragma unroll
        for (int qt = 0; qt < 2; ++qt)
            #pragma unroll
            for (int kf = 0; kf < 2; ++kf)
                pb[qt][kf] = *(const bf16x8*)&PsW[qt * 16 * LD + kf * 32 + lg * 8];
        #pragma unroll
        for (int dt = 0; dt < 4; ++dt)
            #pragma unroll
            for (int kf = 0; kf < 2; ++kf)
                #pragma unroll
                for (int qt = 0; qt < 2; ++qt)
                    o_acc[qt][dt] = mfma16(vfr[dt * 2 + kf], pb[qt][kf], o_acc[qt][dt]);
    };

    // software pipeline: fragments for tile kt+1 prefetched while tile kt computes
    bf16x8 kA[8], vA[8], kB[8], vB[8];
    loadKV(0, kA, vA);
    for (int kt = 0; kt < NKT; kt += 2) {
        loadKV(kt + 1, kB, vB);               // prefetch odd tile
        process(kt, kA, vA);
        if (kt + 2 < NKT) loadKV(kt + 2, kA, vA);  // prefetch next even tile
        process(kt + 1, kB, vB);
    }

    #pragma unroll
    for (int qt = 0; qt < 2; ++qt) {
        float l = l_[qt];
        l += __shfl_xor(l, 16, 64);
        l += __shfl_xor(l, 32, 64);
        float inv = 1.f / l;
        int qq = qw + qt * 16 + lr;
        #pragma unroll
        for (int dt = 0; dt < 4; ++dt) {
            uint2 p;
            p.x = pk2bf(o_acc[qt][dt][0] * inv, o_acc[qt][dt][1] * inv);
            p.y = pk2bf(o_acc[qt][dt][2] * inv, o_acc[qt][dt][3] * inv);
            *(uint2*)&Out[(size_t)(b * S_ + qq) * D_ + h * DK_ + dt * 16 + lg * 4] = p;
        }
    }
}

// ================= output GEMM: A via GLDS16 (bf16), Wo reg-staged fp32 ======
// Round 13: T14 ordering for the Wo path too — loadW(it+1) issued at interval
// top, writeW at interval bottom (same interval; no load crosses a barrier).
// dmaA keeps the verified m97 GLDS16-before-barrier pattern.
__global__ __launch_bounds__(256)
void gemm_out(const unsigned short* __restrict__ Ap,
              const float* __restrict__ Wo,
              const float* __restrict__ bias, float* __restrict__ Cptr)
{
    constexpr int K = D_, N = D_;
    __shared__ unsigned short As[2][128 * 64];
    __shared__ unsigned short Wss[2][64 * 64];

    const int bid = blockIdx.x;                 // 0..511
    const int xcd = bid & 7, sl = bid >> 3;     // sl 0..63
    const int nb = sl >> 2, mloc = sl & 3;
    const int m0 = (mloc * 8 + xcd) * 128, n0 = nb * 64;

    const int tid  = threadIdx.x;
    const int lane = tid & 63, wave = tid >> 6;
    const int lr = lane & 15, lg = lane >> 4;
    const int wm = (wave >> 1) * 64, wn = (wave & 1) * 32;

    int rowA[4], kcA[4], rowW[2], kcW[2];
    #pragma unroll
    for (int j = 0; j < 4; ++j) {
        int L = (wave * 4 + j) * 64 + lane;
        rowA[j] = L >> 3; kcA[j] = (L & 7) ^ (rowA[j] & 7);
    }
    #pragma unroll
    for (int j = 0; j < 2; ++j) {
        int L = (wave * 2 + j) * 64 + lane;
        rowW[j] = L >> 3; kcW[j] = (L & 7) ^ (rowW[j] & 7);
    }

    auto dmaA = [&](int k0, int buf) {
        #pragma unroll
        for (int j = 0; j < 4; ++j)
            GLDS16(Ap + (size_t)(m0 + rowA[j]) * K + k0 + kcA[j] * 8,
                   &As[buf][(wave * 4 + j) * 512 + lane * 8]);
    };

    float4 rw[2][2];
    auto loadW = [&](int k0) {
        #pragma unroll
        for (int j = 0; j < 2; ++j) {
            const float* pw = Wo + (size_t)(n0 + rowW[j]) * K + k0 + kcW[j] * 8;
            rw[j][0] = *(const float4*)pw;
            rw[j][1] = *(const float4*)(pw + 4);
        }
    };
    auto writeW = [&](int buf) {
        #pragma unroll
        for (int j = 0; j < 2; ++j) {
            uint4 p;
            p.x = pk2bf(rw[j][0].x, rw[j][0].y); p.y = pk2bf(rw[j][0].z, rw[j][0].w);
            p.z = pk2bf(rw[j][1].x, rw[j][1].y); p.w = pk2bf(rw[j][1].z, rw[j][1].w);
            *(uint4*)&Wss[buf][(wave * 2 + j) * 512 + lane * 8] = p;
        }
    };

    floatx4 acc[4][2];
    #pragma unroll
    for (int mt = 0; mt < 4; ++mt)
        #pragma unroll
        for (int nt = 0; nt < 2; ++nt)
            acc[mt][nt] = floatx4{0.f, 0.f, 0.f, 0.f};

    dmaA(0, 0);
    loadW(0); writeW(0);
    __syncthreads();                      // drains DMA(0) + ds_writes
    for (int it = 0; it < K / 64; ++it) {
        const int buf = it & 1;
        if (it + 1 < K / 64) { dmaA((it + 1) * 64, buf ^ 1); loadW((it + 1) * 64); }

        #pragma unroll
        for (int kf = 0; kf < 2; ++kf) {
            bf16x8 af[4], bfr[2];
            #pragma unroll
            for (int mt = 0; mt < 4; ++mt) {
                int row = wm + mt * 16 + lr;
                af[mt] = *(const bf16x8*)&As[buf][row * 64 + (((kf * 4 + lg) ^ (lr & 7)) * 8)];
            }
            #pragma unroll
            for (int nt = 0; nt < 2; ++nt) {
                int row = wn + nt * 16 + lr;
                bfr[nt] = *(const bf16x8*)&Wss[buf][row * 64 + (((kf * 4 + lg) ^ (lr & 7)) * 8)];
            }
            #pragma unroll
            for (int mt = 0; mt < 4; ++mt)
                #pragma unroll
                for (int nt = 0; nt < 2; ++nt)
                    acc[mt][nt] = mfma16(af[mt], bfr[nt], acc[mt][nt]);
        }

        if (it + 1 < K / 64) writeW(buf ^ 1);
        __syncthreads();
    }

    #pragma unroll
    for (int nt = 0; nt < 2; ++nt) {
        int col = n0 + wn + nt * 16 + lr;
        float bv2 = bias[col];
        #pragma unroll
        for (int mt = 0; mt < 4; ++mt)
            #pragma unroll
            for (int reg = 0; reg < 4; ++reg) {
                int row = m0 + wm + mt * 16 + lg * 4 + reg;
                Cptr[(size_t)row * N + col] = acc[mt][nt][reg] + bv2;
            }
    }
}

// ================= launch ====================================================
extern "C" void kernel_launch(void* const* d_in, const int* in_sizes, int n_in,
                              void* d_out, int out_size, void* d_ws, size_t ws_size,
                              hipStream_t stream)
{
    const float* query = (const float*)d_in[0];
    const float* key   = (const float*)d_in[1];
    const float* value = (const float*)d_in[2];
    const int*   mask  = (const int*)d_in[3];
    const float* Wq = (const float*)d_in[4];
    const float* bq = (const float*)d_in[5];
    const float* Wk = (const float*)d_in[6];
    const float* bk = (const float*)d_in[7];
    const float* Wv = (const float*)d_in[8];
    const float* bv = (const float*)d_in[9];
    const float* Wo = (const float*)d_in[10];
    const float* bo = (const float*)d_in[11];

    // ws (32 MB used): Qp | KpF | VpF | Ap (8 MB each, bf16)
    unsigned short* Qp  = (unsigned short*)d_ws;
    unsigned short* KpF = Qp  + (size_t)BSROWS * D_;
    unsigned short* VpF = KpF + (size_t)BSROWS * D_;
    unsigned short* Ap  = VpF + (size_t)BSROWS * D_;

    dim3 blk(256);

    // 1024 mask-flag blocks (front) + 768 GEMM blocks in one dispatch
    hipLaunchKernelGGL(gemm_qkv, dim3(1024 + 768), blk, 0, stream,
                       query, key, value, Wq, Wk, Wv, bq, bk, bv, mask,
                       Qp, KpF, VpF);

    // 1-D grid: co-resident pair (id, id+256) shares (h,b); id%8 == h%8 (XCD)
    hipLaunchKernelGGL(attn_flash, dim3(512), blk, 0, stream, Qp, KpF, VpF, mask, Ap);

    hipLaunchKernelGGL(gemm_out, dim3(512), blk, 0, stream, Ap, Wo, bo, (float*)d_out);
}

// Round 10
// 255.202 us; speedup vs baseline: 1.0695x; 1.0695x over previous
//
#include <hip/hip_runtime.h>
#include <hip/hip_bf16.h>
#include <cstdint>

#define DEVINL static __device__ __forceinline__

typedef __attribute__((ext_vector_type(4))) float floatx4;
typedef __attribute__((ext_vector_type(8))) short bf16x8;

DEVINL unsigned short f2bf(float f) {
    union { float f; uint32_t u; } v; v.f = f;
    return (unsigned short)((v.u + 0x7FFFu + ((v.u >> 16) & 1u)) >> 16);
}

DEVINL uint32_t pk2bf(float x, float y) {
    __hip_bfloat162 h = __float22bfloat162_rn(float2{x, y});
    union { __hip_bfloat162 h; uint32_t u; } v; v.h = h;
    return v.u;
}

DEVINL floatx4 mfma16(bf16x8 a, bf16x8 b, floatx4 c) {
    return __builtin_amdgcn_mfma_f32_16x16x32_bf16(a, b, c, 0, 0, 0);
}

// async global->LDS DMA, 16B per lane. LDS dest must be base + lane*16 contiguous.
#define GLDS16(g, l)                                                            \
    __builtin_amdgcn_global_load_lds(                                           \
        (const __attribute__((address_space(1))) void*)(g),                     \
        (__attribute__((address_space(3))) void*)(l), 16, 0, 0)

// ---- problem constants ----
constexpr int B_ = 2, S_ = 2048, D_ = 1024, H_ = 16, DK_ = 64;
constexpr int BSROWS = B_ * S_;  // 4096
constexpr int NQB = S_ / 128;    // 16 q-blocks
constexpr int NKT = S_ / 64;     // 32 k-tiles

// Q pre-scale: 1/sqrt(d_k) * log2(e), so softmax uses raw v_exp_f32 (exp2).
constexpr float QSCALE = 0.18033688011112042f;

// per-tile mask flags (1 = all-nonzero tile -> fast path). Rewritten every call.
__device__ int g_flags[B_ * NQB * NKT];

// ================= fused QKV projection GEMM + mask flags ====================
// Round 14: loop reverted to the verified round-7/8 interval ordering
// (writeStage at top consuming last interval's loads, loadStage(it+2) issued
// before compute, drained by the end-of-interval barrier AFTER compute —
// round-9's "same-interval" variant put the vmcnt wait + ds_writes on the
// critical path and regressed 71->90).
// NEW: z0/z1 epilogues bounce the 128x128 tile through LDS (As is free after
// the loop): phase1 scalar ds_writes into the TARGET layout, barrier, phase2
// 8x uint4 fully-coalesced global stores per thread. Replaces 64 scalar 2B
// global stores per thread (z1's were 16B-strided, 12.5% coalescing).
__global__ __launch_bounds__(256, 2)
void gemm_qkv(const float* __restrict__ q, const float* __restrict__ k,
              const float* __restrict__ v,
              const float* __restrict__ Wq, const float* __restrict__ Wk,
              const float* __restrict__ Wv,
              const float* __restrict__ bq, const float* __restrict__ bk,
              const float* __restrict__ bv,
              const int* __restrict__ mask,
              unsigned short* __restrict__ Qp, unsigned short* __restrict__ KpF,
              unsigned short* __restrict__ VpF)
{
    constexpr int K = D_, N = D_;
    __shared__ unsigned short As[2][128 * 64];
    __shared__ unsigned short Bs[2][128 * 64];
    __shared__ int fflag;

    const int bid = blockIdx.x;

    // ---------------- mask-flag blocks (bid < 1024, front of dispatch) ------
    if (bid < 1024) {
        int mb = bid;                         // (b*16 + qb)*32 + kt
        int kt = mb & 31, qq = (mb >> 5) & 15, b = mb >> 9;
        const int* base = mask + (size_t)(b * S_ + qq * 128) * S_ + kt * 64;
        int ok = 1;
        #pragma unroll
        for (int i = 0; i < 8; ++i) {
            int u = threadIdx.x + 256 * i;
            int row = u >> 4, c = u & 15;
            int4 m = *(const int4*)(base + (size_t)row * S_ + c * 4);
            if ((m.x == 0) | (m.y == 0) | (m.z == 0) | (m.w == 0)) ok = 0;
        }
        if (threadIdx.x == 0) fflag = 1;
        __syncthreads();
        if (!ok) fflag = 0;
        __syncthreads();
        if (threadIdx.x == 0) g_flags[mb] = fflag;
        return;
    }

    // ---------------- GEMM blocks (bid >= 1024) ----------------
    const int gb = bid - 1024;                  // 0..767
    const int xcd = gb & 7, sl = gb >> 3;       // sl 0..95
    const int z = sl >> 5, rr = sl & 31;
    const int nb = rr >> 2, mloc = rr & 3;
    const int m0 = (mloc * 8 + xcd) * 128, n0 = nb * 128;

    const float* A    = z == 0 ? q  : z == 1 ? k  : v;
    const float* W    = z == 0 ? Wq : z == 1 ? Wk : Wv;
    const float* bias = z == 0 ? bq : z == 1 ? bk : bv;

    const int tid  = threadIdx.x;
    const int lane = tid & 63, wave = tid >> 6;
    const int lr = lane & 15, lg = lane >> 4;
    const int wm = (wave >> 1) * 64, wn = (wave & 1) * 64;

    // lane-constant stage descriptors (XOR-8 chunk swizzle, GLDS16-compatible)
    int rowA[4], kcA[4];
    #pragma unroll
    for (int j = 0; j < 4; ++j) {
        int L = (wave * 4 + j) * 64 + lane;
        rowA[j] = L >> 3; kcA[j] = (L & 7) ^ (rowA[j] & 7);
    }

    float4 ra[4][2], rw[4][2];
    auto loadStage = [&](int k0) {
        #pragma unroll
        for (int j = 0; j < 4; ++j) {
            const float* pa = A + (size_t)(m0 + rowA[j]) * K + k0 + kcA[j] * 8;
            ra[j][0] = *(const float4*)pa;
            ra[j][1] = *(const float4*)(pa + 4);
            const float* pw = W + (size_t)(n0 + rowA[j]) * K + k0 + kcA[j] * 8;
            rw[j][0] = *(const float4*)pw;
            rw[j][1] = *(const float4*)(pw + 4);
        }
    };
    auto writeStage = [&](int buf) {
        #pragma unroll
        for (int j = 0; j < 4; ++j) {
            uint4 o;
            o.x = pk2bf(ra[j][0].x, ra[j][0].y); o.y = pk2bf(ra[j][0].z, ra[j][0].w);
            o.z = pk2bf(ra[j][1].x, ra[j][1].y); o.w = pk2bf(ra[j][1].z, ra[j][1].w);
            *(uint4*)&As[buf][(wave * 4 + j) * 512 + lane * 8] = o;
            uint4 p;
            p.x = pk2bf(rw[j][0].x, rw[j][0].y); p.y = pk2bf(rw[j][0].z, rw[j][0].w);
            p.z = pk2bf(rw[j][1].x, rw[j][1].y); p.w = pk2bf(rw[j][1].z, rw[j][1].w);
            *(uint4*)&Bs[buf][(wave * 4 + j) * 512 + lane * 8] = p;
        }
    };

    floatx4 acc[4][4];
    #pragma unroll
    for (int mt = 0; mt < 4; ++mt)
        #pragma unroll
        for (int nt = 0; nt < 4; ++nt)
            acc[mt][nt] = floatx4{0.f, 0.f, 0.f, 0.f};

    loadStage(0);
    writeStage(0);
    loadStage(64);
    __syncthreads();
    for (int it = 0; it < K / 64; ++it) {
        const int buf = it & 1;
        if (it + 1 < K / 64) writeStage(buf ^ 1);   // regs(it+1) -> other buf
        if (it + 2 < K / 64) loadStage((it + 2) * 64);

        #pragma unroll
        for (int kf = 0; kf < 2; ++kf) {
            bf16x8 af[4], bfr[4];
            #pragma unroll
            for (int mt = 0; mt < 4; ++mt) {
                int row = wm + mt * 16 + lr;
                af[mt] = *(const bf16x8*)&As[buf][row * 64 + (((kf * 4 + lg) ^ (lr & 7)) * 8)];
            }
            #pragma unroll
            for (int nt = 0; nt < 4; ++nt) {
                int row = wn + nt * 16 + lr;
                bfr[nt] = *(const bf16x8*)&Bs[buf][row * 64 + (((kf * 4 + lg) ^ (lr & 7)) * 8)];
            }
            #pragma unroll
            for (int mt = 0; mt < 4; ++mt)
                #pragma unroll
                for (int nt = 0; nt < 4; ++nt)
                    acc[mt][nt] = mfma16(af[mt], bfr[nt], acc[mt][nt]);
        }
        __syncthreads();
    }

    // ---- epilogues (C/D layout: col=lane&15, row=quad*4+reg) ----
    // As (both buffers, 32 KB contiguous) is free after the final barrier.
    unsigned short* Cs = &As[0][0];             // 16384 shorts = 128x128 bf16

    if (z == 0) {
        // phase 1: acc -> LDS row-major [row][col] (scalar ds_writes)
        #pragma unroll
        for (int nt = 0; nt < 4; ++nt) {
            int cl = wn + nt * 16 + lr;
            float bv2 = bias[n0 + cl];
            #pragma unroll
            for (int mt = 0; mt < 4; ++mt)
                #pragma unroll
                for (int reg = 0; reg < 4; ++reg) {
                    int rl = wm + mt * 16 + lg * 4 + reg;
                    Cs[rl * 128 + cl] = f2bf((acc[mt][nt][reg] + bv2) * QSCALE);
                }
        }
        __syncthreads();
        // phase 2: coalesced uint4 copy-out (8 per thread)
        #pragma unroll
        for (int i = 0; i < 8; ++i) {
            int e = tid * 8 + i;                // 0..2047 uint4 chunks
            int rl = e >> 4, cc = (e & 15) * 8;
            *(uint4*)&Qp[(size_t)(m0 + rl) * N + n0 + cc] = *(uint4*)&Cs[e * 8];
        }
    } else if (z == 1) {
        // block covers 4 KpF 8KB sub-tiles: (h0+hh, kt0+tt), hh,tt in {0,1}
        const int bb = m0 >> 11, kt0 = (m0 & 2047) >> 6, h0 = n0 >> 6;
        // phase 1: acc -> LDS in exact KpF tile layout
        #pragma unroll
        for (int nt = 0; nt < 4; ++nt) {
            int cl = wn + nt * 16 + lr;
            int hh = cl >> 6, d = cl & 63;
            int kfA = d >> 5, lgA = (d >> 3) & 3, j = d & 7;
            float bv2 = bias[n0 + cl];
            #pragma unroll
            for (int mt = 0; mt < 4; ++mt)
                #pragma unroll
                for (int reg = 0; reg < 4; ++reg) {
                    int tl = wm + mt * 16 + lg * 4 + reg;
                    int tt = tl >> 6, key = tl & 63;
                    int mtA = key >> 4, lrA = key & 15;
                    Cs[(hh * 2 + tt) * 4096 + (kfA * 4 + mtA) * 512 +
                       (lrA + 16 * lgA) * 8 + j] = f2bf(acc[mt][nt][reg] + bv2);
                }
        }
        __syncthreads();
        // phase 2: 4 linear 8KB segment copies, coalesced uint4
        #pragma unroll
        for (int i = 0; i < 8; ++i) {
            int e = tid * 8 + i;                // 0..2047
            int s = e >> 9, w = e & 511;        // sub-tile, chunk within
            int hh = s >> 1, tt = s & 1;
            size_t gbase = (((size_t)(bb * 16 + h0 + hh)) * 32 + (kt0 + tt)) * 4096;
            *(uint4*)&KpF[gbase + w * 8] = *(uint4*)&Cs[e * 8];
        }
    } else {
        #pragma unroll
        for (int nt = 0; nt < 4; ++nt) {
            int c = n0 + wn + nt * 16 + lr;
            int h = c >> 6, dtA = (c >> 4) & 3;   // lrA == lr
            float bv2 = bias[c];
            #pragma unroll
            for (int mt = 0; mt < 4; ++mt) {
                int t0 = m0 + wm + mt * 16 + lg * 4;
                int bb = t0 >> 11, s0 = t0 & (S_ - 1);
                int kt = s0 >> 6, key = s0 & 63;
                int kfA = key >> 5, lgA = (key >> 3) & 3, j0 = key & 7;
                size_t off = (((size_t)(bb * 16 + h) * 32 + kt) * 8 + (dtA * 2 + kfA)) * 512
                           + (lr + 16 * lgA) * 8 + j0;
                uint2 p;
                p.x = pk2bf(acc[mt][nt][0] + bv2, acc[mt][nt][1] + bv2);
                p.y = pk2bf(acc[mt][nt][2] + bv2, acc[mt][nt][3] + bv2);
                *(uint2*)&VpF[off] = p;
            }
        }
    }
}

// ================= Flash attention: zero-barrier, pipelined fragment loads ===
// (verified config: 4 waves x 32 q-rows, 2 blocks/CU; 1-D grid so the
// co-resident pair (id, id+256) shares (h,b) for L1/L2-hot K/V streams;
// id%8 == h%8 keeps XCD clustering. Reg double-buffered K/V prefetch,
// fixed-max exp2 softmax, wave-private P in LDS, no barriers in loop.)
__global__ __launch_bounds__(256, 2)
void attn_flash(const unsigned short* __restrict__ Qp,
                const unsigned short* __restrict__ KpF,
                const unsigned short* __restrict__ VpF,
                const int* __restrict__ mask,
                unsigned short* __restrict__ Out)
{
    constexpr int LD = 72;
    __shared__ unsigned short Ps[128 * LD];

    const int tid = threadIdx.x;
    const int lane = tid & 63, wave = tid >> 6;
    const int lr = lane & 15, lg = lane >> 4;
    const int id = blockIdx.x;                 // 0..511
    const int hb = id & 31;                    // h + 16*b
    const int h = hb & 15, b = hb >> 4;
    const int qb = ((id >> 8) << 3) | ((id >> 5) & 7);
    const int q0 = qb * 128, qw = q0 + wave * 32;

    bf16x8 qf[2][2];
    #pragma unroll
    for (int qt = 0; qt < 2; ++qt)
        #pragma unroll
        for (int kf = 0; kf < 2; ++kf)
            qf[qt][kf] = *(const bf16x8*)(Qp + (size_t)(b * S_ + qw + qt * 16 + lr) * D_ +
                                          h * DK_ + kf * 32 + lg * 8);

    float l_[2] = {0.f, 0.f};
    floatx4 o_acc[2][4];
    #pragma unroll
    for (int qt = 0; qt < 2; ++qt)
        #pragma unroll
        for (int dt = 0; dt < 4; ++dt) o_acc[qt][dt] = floatx4{0.f, 0.f, 0.f, 0.f};

    const unsigned short* kbase = KpF + (size_t)(b * 16 + h) * 32 * 4096 + lane * 8;
    const unsigned short* vbase = VpF + (size_t)(b * 16 + h) * 32 * 4096 + lane * 8;
    const int fbase = (b * NQB + qb) * NKT;
    unsigned short* PsW = &Ps[(wave * 32 + lr) * LD];

    auto loadKV = [&](int kt, bf16x8 (&kfr)[8], bf16x8 (&vfr)[8]) {
        const unsigned short* kb = kbase + kt * 4096;
        const unsigned short* vb = vbase + kt * 4096;
        #pragma unroll
        for (int c = 0; c < 8; ++c) kfr[c] = *(const bf16x8*)(kb + c * 512);
        #pragma unroll
        for (int c = 0; c < 8; ++c) vfr[c] = *(const bf16x8*)(vb + c * 512);
    };

    auto process = [&](int kt, bf16x8 (&kfr)[8], bf16x8 (&vfr)[8]) {
        floatx4 sc[2][4];
        #pragma unroll
        for (int qt = 0; qt < 2; ++qt)
            #pragma unroll
            for (int mt = 0; mt < 4; ++mt) sc[qt][mt] = floatx4{0.f, 0.f, 0.f, 0.f};
        #pragma unroll
        for (int mt = 0; mt < 4; ++mt)
            #pragma unroll
            for (int kf = 0; kf < 2; ++kf)
                #pragma unroll
                for (int qt = 0; qt < 2; ++qt)
                    sc[qt][mt] = mfma16(kfr[kf * 4 + mt], qf[qt][kf], sc[qt][mt]);

        if (g_flags[fbase + kt] == 0) {
            #pragma unroll
            for (int qt = 0; qt < 2; ++qt) {
                int qq = qw + qt * 16 + lr;
                const int* mrow = mask + (size_t)(b * S_ + qq) * S_ + kt * 64;
                #pragma unroll
                for (int mt = 0; mt < 4; ++mt)
                    #pragma unroll
                    for (int reg = 0; reg < 4; ++reg)
                        if (mrow[mt * 16 + lg * 4 + reg] == 0)
                            sc[qt][mt][reg] = -1e9f;
            }
        }

        #pragma unroll
        for (int qt = 0; qt < 2; ++qt) {
            #pragma unroll
            for (int mt = 0; mt < 4; ++mt) {
                float p0 = __builtin_amdgcn_exp2f(sc[qt][mt][0]);
                float p1 = __builtin_amdgcn_exp2f(sc[qt][mt][1]);
                float p2 = __builtin_amdgcn_exp2f(sc[qt][mt][2]);
                float p3 = __builtin_amdgcn_exp2f(sc[qt][mt][3]);
                l_[qt] += (p0 + p1) + (p2 + p3);
                uint2 pk; pk.x = pk2bf(p0, p1); pk.y = pk2bf(p2, p3);
                *(uint2*)&PsW[qt * 16 * LD + mt * 16 + lg * 4] = pk;
            }
        }

        bf16x8 pb[2][2];
        #pragma unroll
        for (int qt = 0; qt < 2; ++qt)
            #pragma unroll
            for (int kf = 0; kf < 2; ++kf)
                pb[qt][kf] = *(const bf16x8*)&PsW[qt * 16 * LD + kf * 32 + lg * 8];
        #pragma unroll
        for (int dt = 0; dt < 4; ++dt)
            #pragma unroll
            for (int kf = 0; kf < 2; ++kf)
                #pragma unroll
                for (int qt = 0; qt < 2; ++qt)
                    o_acc[qt][dt] = mfma16(vfr[dt * 2 + kf], pb[qt][kf], o_acc[qt][dt]);
    };

    // software pipeline: fragments for tile kt+1 prefetched while tile kt computes
    bf16x8 kA[8], vA[8], kB[8], vB[8];
    loadKV(0, kA, vA);
    for (int kt = 0; kt < NKT; kt += 2) {
        loadKV(kt + 1, kB, vB);               // prefetch odd tile
        process(kt, kA, vA);
        if (kt + 2 < NKT) loadKV(kt + 2, kA, vA);  // prefetch next even tile
        process(kt + 1, kB, vB);
    }

    #pragma unroll
    for (int qt = 0; qt < 2; ++qt) {
        float l = l_[qt];
        l += __shfl_xor(l, 16, 64);
        l += __shfl_xor(l, 32, 64);
        float inv = 1.f / l;
        int qq = qw + qt * 16 + lr;
        #pragma unroll
        for (int dt = 0; dt < 4; ++dt) {
            uint2 p;
            p.x = pk2bf(o_acc[qt][dt][0] * inv, o_acc[qt][dt][1] * inv);
            p.y = pk2bf(o_acc[qt][dt][2] * inv, o_acc[qt][dt][3] * inv);
            *(uint2*)&Out[(size_t)(b * S_ + qq) * D_ + h * DK_ + dt * 16 + lg * 4] = p;
        }
    }
}

// ================= output GEMM: A via GLDS16 (bf16), Wo reg-staged fp32 ======
__global__ __launch_bounds__(256)
void gemm_out(const unsigned short* __restrict__ Ap,
              const float* __restrict__ Wo,
              const float* __restrict__ bias, float* __restrict__ Cptr)
{
    constexpr int K = D_, N = D_;
    __shared__ unsigned short As[2][128 * 64];
    __shared__ unsigned short Wss[2][64 * 64];

    const int bid = blockIdx.x;                 // 0..511
    const int xcd = bid & 7, sl = bid >> 3;     // sl 0..63
    const int nb = sl >> 2, mloc = sl & 3;
    const int m0 = (mloc * 8 + xcd) * 128, n0 = nb * 64;

    const int tid  = threadIdx.x;
    const int lane = tid & 63, wave = tid >> 6;
    const int lr = lane & 15, lg = lane >> 4;
    const int wm = (wave >> 1) * 64, wn = (wave & 1) * 32;

    int rowA[4], kcA[4], rowW[2], kcW[2];
    #pragma unroll
    for (int j = 0; j < 4; ++j) {
        int L = (wave * 4 + j) * 64 + lane;
        rowA[j] = L >> 3; kcA[j] = (L & 7) ^ (rowA[j] & 7);
    }
    #pragma unroll
    for (int j = 0; j < 2; ++j) {
        int L = (wave * 2 + j) * 64 + lane;
        rowW[j] = L >> 3; kcW[j] = (L & 7) ^ (rowW[j] & 7);
    }

    auto dmaA = [&](int k0, int buf) {
        #pragma unroll
        for (int j = 0; j < 4; ++j)
            GLDS16(Ap + (size_t)(m0 + rowA[j]) * K + k0 + kcA[j] * 8,
                   &As[buf][(wave * 4 + j) * 512 + lane * 8]);
    };

    float4 rw[2][2];
    auto loadW = [&](int k0) {
        #pragma unroll
        for (int j = 0; j < 2; ++j) {
            const float* pw = Wo + (size_t)(n0 + rowW[j]) * K + k0 + kcW[j] * 8;
            rw[j][0] = *(const float4*)pw;
            rw[j][1] = *(const float4*)(pw + 4);
        }
    };
    auto writeW = [&](int buf) {
        #pragma unroll
        for (int j = 0; j < 2; ++j) {
            uint4 p;
            p.x = pk2bf(rw[j][0].x, rw[j][0].y); p.y = pk2bf(rw[j][0].z, rw[j][0].w);
            p.z = pk2bf(rw[j][1].x, rw[j][1].y); p.w = pk2bf(rw[j][1].z, rw[j][1].w);
            *(uint4*)&Wss[buf][(wave * 2 + j) * 512 + lane * 8] = p;
        }
    };

    floatx4 acc[4][2];
    #pragma unroll
    for (int mt = 0; mt < 4; ++mt)
        #pragma unroll
        for (int nt = 0; nt < 2; ++nt)
            acc[mt][nt] = floatx4{0.f, 0.f, 0.f, 0.f};

    dmaA(0, 0);
    loadW(0); writeW(0); loadW(64);
    __syncthreads();                      // drains DMA(0) + ds_writes
    for (int it = 0; it < K / 64; ++it) {
        const int buf = it & 1;
        if (it + 1 < K / 64) { dmaA((it + 1) * 64, buf ^ 1); writeW(buf ^ 1); }
        if (it + 2 < K / 64) loadW((it + 2) * 64);

        #pragma unroll
        for (int kf = 0; kf < 2; ++kf) {
            bf16x8 af[4], bfr[2];
            #pragma unroll
            for (int mt = 0; mt < 4; ++mt) {
                int row = wm + mt * 16 + lr;
                af[mt] = *(const bf16x8*)&As[buf][row * 64 + (((kf * 4 + lg) ^ (lr & 7)) * 8)];
            }
            #pragma unroll
            for (int nt = 0; nt < 2; ++nt) {
                int row = wn + nt * 16 + lr;
                bfr[nt] = *(const bf16x8*)&Wss[buf][row * 64 + (((kf * 4 + lg) ^ (lr & 7)) * 8)];
            }
            #pragma unroll
            for (int mt = 0; mt < 4; ++mt)
                #pragma unroll
                for (int nt = 0; nt < 2; ++nt)
                    acc[mt][nt] = mfma16(af[mt], bfr[nt], acc[mt][nt]);
        }
        __syncthreads();
    }

    #pragma unroll
    for (int nt = 0; nt < 2; ++nt) {
        int col = n0 + wn + nt * 16 + lr;
        float bv2 = bias[col];
        #pragma unroll
        for (int mt = 0; mt < 4; ++mt)
            #pragma unroll
            for (int reg = 0; reg < 4; ++reg) {
                int row = m0 + wm + mt * 16 + lg * 4 + reg;
                Cptr[(size_t)row * N + col] = acc[mt][nt][reg] + bv2;
            }
    }
}

// ================= launch ====================================================
extern "C" void kernel_launch(void* const* d_in, const int* in_sizes, int n_in,
                              void* d_out, int out_size, void* d_ws, size_t ws_size,
                              hipStream_t stream)
{
    const float* query = (const float*)d_in[0];
    const float* key   = (const float*)d_in[1];
    const float* value = (const float*)d_in[2];
    const int*   mask  = (const int*)d_in[3];
    const float* Wq = (const float*)d_in[4];
    const float* bq = (const float*)d_in[5];
    const float* Wk = (const float*)d_in[6];
    const float* bk = (const float*)d_in[7];
    const float* Wv = (const float*)d_in[8];
    const float* bv = (const float*)d_in[9];
    const float* Wo = (const float*)d_in[10];
    const float* bo = (const float*)d_in[11];

    // ws (32 MB used): Qp | KpF | VpF | Ap (8 MB each, bf16)
    unsigned short* Qp  = (unsigned short*)d_ws;
    unsigned short* KpF = Qp  + (size_t)BSROWS * D_;
    unsigned short* VpF = KpF + (size_t)BSROWS * D_;
    unsigned short* Ap  = VpF + (size_t)BSROWS * D_;

    dim3 blk(256);

    // 1024 mask-flag blocks (front) + 768 GEMM blocks in one dispatch
    hipLaunchKernelGGL(gemm_qkv, dim3(1024 + 768), blk, 0, stream,
                       query, key, value, Wq, Wk, Wv, bq, bk, bv, mask,
                       Qp, KpF, VpF);

    // 1-D grid: co-resident pair (id, id+256) shares (h,b); id%8 == h%8 (XCD)
    hipLaunchKernelGGL(attn_flash, dim3(512), blk, 0, stream, Qp, KpF, VpF, mask, Ap);

    hipLaunchKernelGGL(gemm_out, dim3(512), blk, 0, stream, Ap, Wo, bo, (float*)d_out);
}

// Round 11
// 243.120 us; speedup vs baseline: 1.1227x; 1.0497x over previous
//
#include <hip/hip_runtime.h>
#include <hip/hip_bf16.h>
#include <cstdint>

#define DEVINL static __device__ __forceinline__

typedef __attribute__((ext_vector_type(4))) float floatx4;
typedef __attribute__((ext_vector_type(8))) short bf16x8;

DEVINL unsigned short f2bf(float f) {
    union { float f; uint32_t u; } v; v.f = f;
    return (unsigned short)((v.u + 0x7FFFu + ((v.u >> 16) & 1u)) >> 16);
}

DEVINL uint32_t pk2bf(float x, float y) {
    __hip_bfloat162 h = __float22bfloat162_rn(float2{x, y});
    union { __hip_bfloat162 h; uint32_t u; } v; v.h = h;
    return v.u;
}

DEVINL floatx4 mfma16(bf16x8 a, bf16x8 b, floatx4 c) {
    return __builtin_amdgcn_mfma_f32_16x16x32_bf16(a, b, c, 0, 0, 0);
}

// async global->LDS DMA, 16B per lane. LDS dest must be base + lane*16 contiguous.
#define GLDS16(g, l)                                                            \
    __builtin_amdgcn_global_load_lds(                                           \
        (const __attribute__((address_space(1))) void*)(g),                     \
        (__attribute__((address_space(3))) void*)(l), 16, 0, 0)

// ---- problem constants ----
constexpr int B_ = 2, S_ = 2048, D_ = 1024, H_ = 16, DK_ = 64;
constexpr int BSROWS = B_ * S_;  // 4096
constexpr int NQB = S_ / 128;    // 16 q-blocks
constexpr int NKT = S_ / 64;     // 32 k-tiles

// Q pre-scale: 1/sqrt(d_k) * log2(e), so softmax uses raw v_exp_f32 (exp2).
constexpr float QSCALE = 0.18033688011112042f;

// per-tile mask flags (1 = all-nonzero tile -> fast path). Rewritten every call.
__device__ int g_flags[B_ * NQB * NKT];

// ================= fused QKV projection GEMM + mask flags + Wo conv ==========
// Round 15 CONSOLIDATION: every piece reverted to its best VERIFIED form.
// - GEMM loop: the 71-us round-7-measured ordering (writeStage at interval
//   top consuming last interval's loads, loadStage(it+2) issued before
//   compute, drained by the end-of-interval barrier). BK=64, 2 blocks/CU.
// - Epilogues: direct stores (round-10's LDS bounce regressed 71->78).
// - Flag blocks at bid>=768 (as in the 71-us build).
// - NEW (cheap): bid>=1792 tail blocks convert Wo fp32->bf16 into wob so
//   gemm_out can revert to its verified dual-GLDS16 form (round-7's
//   reg-staged Wo crossed barriers = serial drain).
__global__ __launch_bounds__(256, 2)
void gemm_qkv(const float* __restrict__ q, const float* __restrict__ k,
              const float* __restrict__ v,
              const float* __restrict__ Wq, const float* __restrict__ Wk,
              const float* __restrict__ Wv, const float* __restrict__ Wo,
              const float* __restrict__ bq, const float* __restrict__ bk,
              const float* __restrict__ bv,
              const int* __restrict__ mask,
              unsigned short* __restrict__ Qp, unsigned short* __restrict__ KpF,
              unsigned short* __restrict__ VpF, unsigned short* __restrict__ wob)
{
    constexpr int K = D_, N = D_;
    __shared__ unsigned short As[2][128 * 64];
    __shared__ unsigned short Bs[2][128 * 64];
    __shared__ int fflag;

    const int bid = blockIdx.x;

    // ---------------- Wo fp32->bf16 conversion blocks (bid >= 1792) ---------
    if (bid >= 1792) {
        int rb = bid - 1792;                  // 0..511
        size_t e = ((size_t)rb * 256 + threadIdx.x) * 8;
        float4 v0 = *(const float4*)(Wo + e);
        float4 v1 = *(const float4*)(Wo + e + 4);
        uint4 o;
        o.x = pk2bf(v0.x, v0.y); o.y = pk2bf(v0.z, v0.w);
        o.z = pk2bf(v1.x, v1.y); o.w = pk2bf(v1.z, v1.w);
        *(uint4*)(wob + e) = o;
        return;
    }

    // ---------------- mask-flag blocks (768 <= bid < 1792) ------------------
    if (bid >= 768) {
        int mb = bid - 768;                   // (b*16 + qb)*32 + kt
        int kt = mb & 31, qq = (mb >> 5) & 15, b = mb >> 9;
        const int* base = mask + (size_t)(b * S_ + qq * 128) * S_ + kt * 64;
        int ok = 1;
        #pragma unroll
        for (int i = 0; i < 8; ++i) {
            int u = threadIdx.x + 256 * i;
            int row = u >> 4, c = u & 15;
            int4 m = *(const int4*)(base + (size_t)row * S_ + c * 4);
            if ((m.x == 0) | (m.y == 0) | (m.z == 0) | (m.w == 0)) ok = 0;
        }
        if (threadIdx.x == 0) fflag = 1;
        __syncthreads();
        if (!ok) fflag = 0;
        __syncthreads();
        if (threadIdx.x == 0) g_flags[mb] = fflag;
        return;
    }

    // ---------------- GEMM blocks (bid < 768) ----------------
    const int gb = bid;                         // 0..767
    const int xcd = gb & 7, sl = gb >> 3;       // sl 0..95
    const int z = sl >> 5, rr = sl & 31;
    const int nb = rr >> 2, mloc = rr & 3;
    const int m0 = (mloc * 8 + xcd) * 128, n0 = nb * 128;

    const float* A    = z == 0 ? q  : z == 1 ? k  : v;
    const float* W    = z == 0 ? Wq : z == 1 ? Wk : Wv;
    const float* bias = z == 0 ? bq : z == 1 ? bk : bv;

    const int tid  = threadIdx.x;
    const int lane = tid & 63, wave = tid >> 6;
    const int lr = lane & 15, lg = lane >> 4;
    const int wm = (wave >> 1) * 64, wn = (wave & 1) * 64;

    // lane-constant stage descriptors (XOR-8 chunk swizzle, GLDS16-compatible)
    int rowA[4], kcA[4];
    #pragma unroll
    for (int j = 0; j < 4; ++j) {
        int L = (wave * 4 + j) * 64 + lane;
        rowA[j] = L >> 3; kcA[j] = (L & 7) ^ (rowA[j] & 7);
    }

    float4 ra[4][2], rw[4][2];
    auto loadStage = [&](int k0) {
        #pragma unroll
        for (int j = 0; j < 4; ++j) {
            const float* pa = A + (size_t)(m0 + rowA[j]) * K + k0 + kcA[j] * 8;
            ra[j][0] = *(const float4*)pa;
            ra[j][1] = *(const float4*)(pa + 4);
            const float* pw = W + (size_t)(n0 + rowA[j]) * K + k0 + kcA[j] * 8;
            rw[j][0] = *(const float4*)pw;
            rw[j][1] = *(const float4*)(pw + 4);
        }
    };
    auto writeStage = [&](int buf) {
        #pragma unroll
        for (int j = 0; j < 4; ++j) {
            uint4 o;
            o.x = pk2bf(ra[j][0].x, ra[j][0].y); o.y = pk2bf(ra[j][0].z, ra[j][0].w);
            o.z = pk2bf(ra[j][1].x, ra[j][1].y); o.w = pk2bf(ra[j][1].z, ra[j][1].w);
            *(uint4*)&As[buf][(wave * 4 + j) * 512 + lane * 8] = o;
            uint4 p;
            p.x = pk2bf(rw[j][0].x, rw[j][0].y); p.y = pk2bf(rw[j][0].z, rw[j][0].w);
            p.z = pk2bf(rw[j][1].x, rw[j][1].y); p.w = pk2bf(rw[j][1].z, rw[j][1].w);
            *(uint4*)&Bs[buf][(wave * 4 + j) * 512 + lane * 8] = p;
        }
    };

    floatx4 acc[4][4];
    #pragma unroll
    for (int mt = 0; mt < 4; ++mt)
        #pragma unroll
        for (int nt = 0; nt < 4; ++nt)
            acc[mt][nt] = floatx4{0.f, 0.f, 0.f, 0.f};

    loadStage(0);
    writeStage(0);
    loadStage(64);
    __syncthreads();
    for (int it = 0; it < K / 64; ++it) {
        const int buf = it & 1;
        if (it + 1 < K / 64) writeStage(buf ^ 1);   // regs(it+1) -> other buf
        if (it + 2 < K / 64) loadStage((it + 2) * 64);

        #pragma unroll
        for (int kf = 0; kf < 2; ++kf) {
            bf16x8 af[4], bfr[4];
            #pragma unroll
            for (int mt = 0; mt < 4; ++mt) {
                int row = wm + mt * 16 + lr;
                af[mt] = *(const bf16x8*)&As[buf][row * 64 + (((kf * 4 + lg) ^ (lr & 7)) * 8)];
            }
            #pragma unroll
            for (int nt = 0; nt < 4; ++nt) {
                int row = wn + nt * 16 + lr;
                bfr[nt] = *(const bf16x8*)&Bs[buf][row * 64 + (((kf * 4 + lg) ^ (lr & 7)) * 8)];
            }
            #pragma unroll
            for (int mt = 0; mt < 4; ++mt)
                #pragma unroll
                for (int nt = 0; nt < 4; ++nt)
                    acc[mt][nt] = mfma16(af[mt], bfr[nt], acc[mt][nt]);
        }
        __syncthreads();
    }

    // ---- epilogues (direct stores; C/D layout: col=lane&15, row=quad*4+reg) -
    if (z == 0) {
        #pragma unroll
        for (int nt = 0; nt < 4; ++nt) {
            int col = n0 + wn + nt * 16 + lr;
            float bv2 = bias[col];
            #pragma unroll
            for (int mt = 0; mt < 4; ++mt)
                #pragma unroll
                for (int reg = 0; reg < 4; ++reg) {
                    int row = m0 + wm + mt * 16 + lg * 4 + reg;
                    Qp[(size_t)row * N + col] = f2bf((acc[mt][nt][reg] + bv2) * QSCALE);
                }
        }
    } else if (z == 1) {
        #pragma unroll
        for (int nt = 0; nt < 4; ++nt) {
            int c = n0 + wn + nt * 16 + lr;
            int h = c >> 6, d = c & 63;
            int kfA = d >> 5, lgA = (d >> 3) & 3, j = d & 7;
            float bv2 = bias[c];
            #pragma unroll
            for (int mt = 0; mt < 4; ++mt)
                #pragma unroll
                for (int reg = 0; reg < 4; ++reg) {
                    int t = m0 + wm + mt * 16 + lg * 4 + reg;
                    int bb = t >> 11, sx = t & (S_ - 1);
                    int kt = sx >> 6, key = sx & 63;
                    int mtA = key >> 4, lrA = key & 15;
                    size_t off = (((size_t)(bb * 16 + h) * 32 + kt) * 8 + (kfA * 4 + mtA)) * 512
                               + (lrA + 16 * lgA) * 8 + j;
                    KpF[off] = f2bf(acc[mt][nt][reg] + bv2);
                }
        }
    } else {
        #pragma unroll
        for (int nt = 0; nt < 4; ++nt) {
            int c = n0 + wn + nt * 16 + lr;
            int h = c >> 6, dtA = (c >> 4) & 3;   // lrA == lr
            float bv2 = bias[c];
            #pragma unroll
            for (int mt = 0; mt < 4; ++mt) {
                int t0 = m0 + wm + mt * 16 + lg * 4;
                int bb = t0 >> 11, s0 = t0 & (S_ - 1);
                int kt = s0 >> 6, key = s0 & 63;
                int kfA = key >> 5, lgA = (key >> 3) & 3, j0 = key & 7;
                size_t off = (((size_t)(bb * 16 + h) * 32 + kt) * 8 + (dtA * 2 + kfA)) * 512
                           + (lr + 16 * lgA) * 8 + j0;
                uint2 p;
                p.x = pk2bf(acc[mt][nt][0] + bv2, acc[mt][nt][1] + bv2);
                p.y = pk2bf(acc[mt][nt][2] + bv2, acc[mt][nt][3] + bv2);
                *(uint2*)&VpF[off] = p;
            }
        }
    }
}

// ================= Flash attention: zero-barrier, pipelined fragment loads ===
// Reverted to the VERIFIED 53-55 us config (measured rounds 1 and 6):
// grid (h,qb,b), 4 waves x 32 q-rows, 2 blocks/CU; id%8 == h%8 -> a head's
// K/V stays XCD-L2-resident. S^T = K*Q^T, O^T = V^T*P^T, fixed-max exp2
// softmax (Q pre-scaled by log2e/8), wave-private P in LDS, no barriers in
// loop. K/V fragment loads software-pipelined one tile ahead (unroll-2).
// (Round-7's 1-D co-residency remap was never validated -> dropped.)
__global__ __launch_bounds__(256, 2)
void attn_flash(const unsigned short* __restrict__ Qp,
                const unsigned short* __restrict__ KpF,
                const unsigned short* __restrict__ VpF,
                const int* __restrict__ mask,
                unsigned short* __restrict__ Out)
{
    constexpr int LD = 72;
    __shared__ unsigned short Ps[128 * LD];

    const int tid = threadIdx.x;
    const int lane = tid & 63, wave = tid >> 6;
    const int lr = lane & 15, lg = lane >> 4;
    const int h = blockIdx.x, qb = blockIdx.y, b = blockIdx.z;
    const int q0 = qb * 128, qw = q0 + wave * 32;

    bf16x8 qf[2][2];
    #pragma unroll
    for (int qt = 0; qt < 2; ++qt)
        #pragma unroll
        for (int kf = 0; kf < 2; ++kf)
            qf[qt][kf] = *(const bf16x8*)(Qp + (size_t)(b * S_ + qw + qt * 16 + lr) * D_ +
                                          h * DK_ + kf * 32 + lg * 8);

    float l_[2] = {0.f, 0.f};
    floatx4 o_acc[2][4];
    #pragma unroll
    for (int qt = 0; qt < 2; ++qt)
        #pragma unroll
        for (int dt = 0; dt < 4; ++dt) o_acc[qt][dt] = floatx4{0.f, 0.f, 0.f, 0.f};

    const unsigned short* kbase = KpF + (size_t)(b * 16 + h) * 32 * 4096 + lane * 8;
    const unsigned short* vbase = VpF + (size_t)(b * 16 + h) * 32 * 4096 + lane * 8;
    const int fbase = (b * NQB + qb) * NKT;
    unsigned short* PsW = &Ps[(wave * 32 + lr) * LD];

    auto loadKV = [&](int kt, bf16x8 (&kfr)[8], bf16x8 (&vfr)[8]) {
        const unsigned short* kb = kbase + kt * 4096;
        const unsigned short* vb = vbase + kt * 4096;
        #pragma unroll
        for (int c = 0; c < 8; ++c) kfr[c] = *(const bf16x8*)(kb + c * 512);
        #pragma unroll
        for (int c = 0; c < 8; ++c) vfr[c] = *(const bf16x8*)(vb + c * 512);
    };

    auto process = [&](int kt, bf16x8 (&kfr)[8], bf16x8 (&vfr)[8]) {
        floatx4 sc[2][4];
        #pragma unroll
        for (int qt = 0; qt < 2; ++qt)
            #pragma unroll
            for (int mt = 0; mt < 4; ++mt) sc[qt][mt] = floatx4{0.f, 0.f, 0.f, 0.f};
        #pragma unroll
        for (int mt = 0; mt < 4; ++mt)
            #pragma unroll
            for (int kf = 0; kf < 2; ++kf)
                #pragma unroll
                for (int qt = 0; qt < 2; ++qt)
                    sc[qt][mt] = mfma16(kfr[kf * 4 + mt], qf[qt][kf], sc[qt][mt]);

        if (g_flags[fbase + kt] == 0) {
            #pragma unroll
            for (int qt = 0; qt < 2; ++qt) {
                int qq = qw + qt * 16 + lr;
                const int* mrow = mask + (size_t)(b * S_ + qq) * S_ + kt * 64;
                #pragma unroll
                for (int mt = 0; mt < 4; ++mt)
                    #pragma unroll
                    for (int reg = 0; reg < 4; ++reg)
                        if (mrow[mt * 16 + lg * 4 + reg] == 0)
                            sc[qt][mt][reg] = -1e9f;
            }
        }

        #pragma unroll
        for (int qt = 0; qt < 2; ++qt) {
            #pragma unroll
            for (int mt = 0; mt < 4; ++mt) {
                float p0 = __builtin_amdgcn_exp2f(sc[qt][mt][0]);
                float p1 = __builtin_amdgcn_exp2f(sc[qt][mt][1]);
                float p2 = __builtin_amdgcn_exp2f(sc[qt][mt][2]);
                float p3 = __builtin_amdgcn_exp2f(sc[qt][mt][3]);
                l_[qt] += (p0 + p1) + (p2 + p3);
                uint2 pk; pk.x = pk2bf(p0, p1); pk.y = pk2bf(p2, p3);
                *(uint2*)&PsW[qt * 16 * LD + mt * 16 + lg * 4] = pk;
            }
        }

        bf16x8 pb[2][2];
        #pragma unroll
        for (int qt = 0; qt < 2; ++qt)
            #pragma unroll
            for (int kf = 0; kf < 2; ++kf)
                pb[qt][kf] = *(const bf16x8*)&PsW[qt * 16 * LD + kf * 32 + lg * 8];
        #pragma unroll
        for (int dt = 0; dt < 4; ++dt)
            #pragma unroll
            for (int kf = 0; kf < 2; ++kf)
                #pragma unroll
                for (int qt = 0; qt < 2; ++qt)
                    o_acc[qt][dt] = mfma16(vfr[dt * 2 + kf], pb[qt][kf], o_acc[qt][dt]);
    };

    // software pipeline: fragments for tile kt+1 prefetched while tile kt computes
    bf16x8 kA[8], vA[8], kB[8], vB[8];
    loadKV(0, kA, vA);
    for (int kt = 0; kt < NKT; kt += 2) {
        loadKV(kt + 1, kB, vB);               // prefetch odd tile
        process(kt, kA, vA);
        if (kt + 2 < NKT) loadKV(kt + 2, kA, vA);  // prefetch next even tile
        process(kt + 1, kB, vB);
    }

    #pragma unroll
    for (int qt = 0; qt < 2; ++qt) {
        float l = l_[qt];
        l += __shfl_xor(l, 16, 64);
        l += __shfl_xor(l, 32, 64);
        float inv = 1.f / l;
        int qq = qw + qt * 16 + lr;
        #pragma unroll
        for (int dt = 0; dt < 4; ++dt) {
            uint2 p;
            p.x = pk2bf(o_acc[qt][dt][0] * inv, o_acc[qt][dt][1] * inv);
            p.y = pk2bf(o_acc[qt][dt][2] * inv, o_acc[qt][dt][3] * inv);
            *(uint2*)&Out[(size_t)(b * S_ + qq) * D_ + h * DK_ + dt * 16 + lg * 4] = p;
        }
    }
}

// ================= output GEMM: dual-GLDS16 (verified rounds 0-6) ============
// Reverted: both A (bf16 Ap) and W (bf16 wob, converted by gemm_qkv tail
// blocks) staged via global_load_lds double-buffer with one __syncthreads per
// iteration — the m97-pattern that measured ~20-25 us. (Round-7's reg-staged
// fp32 Wo crossed barriers -> serial vmcnt drain.)
__global__ __launch_bounds__(256)
void gemm_out(const unsigned short* __restrict__ Ap,
              const unsigned short* __restrict__ Wb,
              const float* __restrict__ bias, float* __restrict__ Cptr)
{
    constexpr int K = D_, N = D_;
    __shared__ unsigned short As[2][128 * 64];
    __shared__ unsigned short Wss[2][64 * 64];

    const int bid = blockIdx.x;                 // 0..511
    const int xcd = bid & 7, sl = bid >> 3;     // sl 0..63
    const int nb = sl >> 2, mloc = sl & 3;
    const int m0 = (mloc * 8 + xcd) * 128, n0 = nb * 64;

    const int tid  = threadIdx.x;
    const int lane = tid & 63, wave = tid >> 6;
    const int lr = lane & 15, lg = lane >> 4;
    const int wm = (wave >> 1) * 64, wn = (wave & 1) * 32;

    int rowA[4], kcA[4], rowW[2], kcW[2];
    #pragma unroll
    for (int j = 0; j < 4; ++j) {
        int L = (wave * 4 + j) * 64 + lane;
        rowA[j] = L >> 3; kcA[j] = (L & 7) ^ (rowA[j] & 7);
    }
    #pragma unroll
    for (int j = 0; j < 2; ++j) {
        int L = (wave * 2 + j) * 64 + lane;
        rowW[j] = L >> 3; kcW[j] = (L & 7) ^ (rowW[j] & 7);
    }

    auto dma = [&](int k0, int buf) {
        #pragma unroll
        for (int j = 0; j < 4; ++j)
            GLDS16(Ap + (size_t)(m0 + rowA[j]) * K + k0 + kcA[j] * 8,
                   &As[buf][(wave * 4 + j) * 512 + lane * 8]);
        #pragma unroll
        for (int j = 0; j < 2; ++j)
            GLDS16(Wb + (size_t)(n0 + rowW[j]) * K + k0 + kcW[j] * 8,
                   &Wss[buf][(wave * 2 + j) * 512 + lane * 8]);
    };

    floatx4 acc[4][2];
    #pragma unroll
    for (int mt = 0; mt < 4; ++mt)
        #pragma unroll
        for (int nt = 0; nt < 2; ++nt)
            acc[mt][nt] = floatx4{0.f, 0.f, 0.f, 0.f};

    dma(0, 0);
    for (int it = 0; it < K / 64; ++it) {
        __syncthreads();
        if (it + 1 < K / 64) dma((it + 1) * 64, (it + 1) & 1);
        const int buf = it & 1;

        #pragma unroll
        for (int kf = 0; kf < 2; ++kf) {
            bf16x8 af[4], bfr[2];
            #pragma unroll
            for (int mt = 0; mt < 4; ++mt) {
                int row = wm + mt * 16 + lr;
                af[mt] = *(const bf16x8*)&As[buf][row * 64 + (((kf * 4 + lg) ^ (lr & 7)) * 8)];
            }
            #pragma unroll
            for (int nt = 0; nt < 2; ++nt) {
                int row = wn + nt * 16 + lr;
                bfr[nt] = *(const bf16x8*)&Wss[buf][row * 64 + (((kf * 4 + lg) ^ (lr & 7)) * 8)];
            }
            #pragma unroll
            for (int mt = 0; mt < 4; ++mt)
                #pragma unroll
                for (int nt = 0; nt < 2; ++nt)
                    acc[mt][nt] = mfma16(af[mt], bfr[nt], acc[mt][nt]);
        }
    }

    #pragma unroll
    for (int nt = 0; nt < 2; ++nt) {
        int col = n0 + wn + nt * 16 + lr;
        float bv2 = bias[col];
        #pragma unroll
        for (int mt = 0; mt < 4; ++mt)
            #pragma unroll
            for (int reg = 0; reg < 4; ++reg) {
                int row = m0 + wm + mt * 16 + lg * 4 + reg;
                Cptr[(size_t)row * N + col] = acc[mt][nt][reg] + bv2;
            }
    }
}

// ================= launch ====================================================
extern "C" void kernel_launch(void* const* d_in, const int* in_sizes, int n_in,
                              void* d_out, int out_size, void* d_ws, size_t ws_size,
                              hipStream_t stream)
{
    const float* query = (const float*)d_in[0];
    const float* key   = (const float*)d_in[1];
    const float* value = (const float*)d_in[2];
    const int*   mask  = (const int*)d_in[3];
    const float* Wq = (const float*)d_in[4];
    const float* bq = (const float*)d_in[5];
    const float* Wk = (const float*)d_in[6];
    const float* bk = (const float*)d_in[7];
    const float* Wv = (const float*)d_in[8];
    const float* bv = (const float*)d_in[9];
    const float* Wo = (const float*)d_in[10];
    const float* bo = (const float*)d_in[11];

    // ws (34 MB used): Qp | KpF | VpF | Ap (8 MB each) | wob (2 MB)
    unsigned short* Qp  = (unsigned short*)d_ws;
    unsigned short* KpF = Qp  + (size_t)BSROWS * D_;
    unsigned short* VpF = KpF + (size_t)BSROWS * D_;
    unsigned short* Ap  = VpF + (size_t)BSROWS * D_;
    unsigned short* wob = Ap  + (size_t)BSROWS * D_;

    dim3 blk(256);

    // 768 GEMM + 1024 mask-flag + 512 Wo-conversion blocks in one dispatch
    hipLaunchKernelGGL(gemm_qkv, dim3(768 + 1024 + 512), blk, 0, stream,
                       query, key, value, Wq, Wk, Wv, Wo, bq, bk, bv, mask,
                       Qp, KpF, VpF, wob);

    dim3 gattn(H_, NQB, B_);               // (16, 16, 2): id%8 == h%8 (XCD L2)
    hipLaunchKernelGGL(attn_flash, gattn, blk, 0, stream, Qp, KpF, VpF, mask, Ap);

    hipLaunchKernelGGL(gemm_out, dim3(512), blk, 0, stream, Ap, wob, bo, (float*)d_out);
}